// Round 1
// baseline (339.349 us; speedup 1.0000x reference)
//
#include <hip/hip_runtime.h>
#include <hip/hip_bf16.h>

typedef __bf16 bf16x8 __attribute__((ext_vector_type(8)));
typedef float f32x4 __attribute__((ext_vector_type(4)));

#define NB 16
#define NC 256
#define NHW 3136
#define NW 56

__device__ __forceinline__ unsigned short f2bf(float f) {
    union { float f; unsigned u; } v; v.f = f;
    unsigned r = v.u + 0x7FFFu + ((v.u >> 16) & 1u);
    return (unsigned short)(r >> 16);
}

// ---------- kernel 1: x NCHW f32 -> NHWC bf16 ----------
__global__ void k_repack_x(const float* __restrict__ x, unsigned short* __restrict__ xT) {
    __shared__ float tile[32][33];
    int bid = blockIdx.x;
    int hwb = bid % 98;
    int cb = (bid / 98) % 8;
    int b = bid / (98 * 8);
    int tid = threadIdx.x;
    {
        int c_l = tid >> 5, hw_l = tid & 31;
        const float* src = x + ((size_t)b * NC + (size_t)cb * 32) * NHW + hwb * 32;
#pragma unroll
        for (int r = 0; r < 4; ++r) {
            int c = c_l + r * 8;
            tile[c][hw_l] = src[(size_t)c * NHW + hw_l];
        }
    }
    __syncthreads();
    {
        int c2 = tid & 31, hw2 = tid >> 5;
        unsigned short* dst = xT + ((size_t)b * NHW + (size_t)hwb * 32) * NC + cb * 32;
#pragma unroll
        for (int r = 0; r < 4; ++r) {
            int hw = hw2 + r * 8;
            dst[(size_t)hw * NC + c2] = f2bf(tile[c2][hw]);
        }
    }
}

// ---------- kernel 2: weight repack ----------
// Bp[tap][icb][n][ic32] bf16  (9*8*256*32 = 589824)
// then transposed center-tap fp32 mats: w01T,w02T,w03T,w04T [i*256+o], fc1T [i*256+o],
// w1T [i*64+o], w2c [i]
__global__ void k_repack_w(const float* __restrict__ w0_0, const float* __restrict__ w0_1,
                           const float* __restrict__ w0_2, const float* __restrict__ w0_3,
                           const float* __restrict__ w0_4, const float* __restrict__ w1,
                           const float* __restrict__ w2, const float* __restrict__ fc1_w,
                           unsigned short* __restrict__ Bp, float* __restrict__ w01T,
                           float* __restrict__ w02T, float* __restrict__ w03T,
                           float* __restrict__ w04T, float* __restrict__ fc1T,
                           float* __restrict__ w1T, float* __restrict__ w2c) {
    int idx = blockIdx.x * 256 + threadIdx.x;
    if (idx < 589824) {
        int q = idx & 31;
        int n = (idx >> 5) & 255;
        int s = idx >> 13;            // 0..71 = tap*8 + icb
        int tap = s >> 3;
        int ic = (s & 7) * 32 + q;
        Bp[idx] = f2bf(w0_0[(size_t)n * 2304 + (size_t)ic * 9 + tap]);
        return;
    }
    int t = idx - 589824;
    if (t < 65536) { w01T[t] = w0_1[(size_t)(t & 255) * 2304 + (size_t)(t >> 8) * 9 + 4]; return; }
    t -= 65536;
    if (t < 65536) { w02T[t] = w0_2[(size_t)(t & 255) * 2304 + (size_t)(t >> 8) * 9 + 4]; return; }
    t -= 65536;
    if (t < 65536) { w03T[t] = w0_3[(size_t)(t & 255) * 2304 + (size_t)(t >> 8) * 9 + 4]; return; }
    t -= 65536;
    if (t < 65536) { w04T[t] = w0_4[(size_t)(t & 255) * 2304 + (size_t)(t >> 8) * 9 + 4]; return; }
    t -= 65536;
    if (t < 65536) { fc1T[t] = fc1_w[(size_t)(t & 255) * 256 + (t >> 8)]; return; }
    t -= 65536;
    if (t < 16384) { w1T[t] = w1[(size_t)(t & 63) * 2304 + (size_t)(t >> 6) * 9 + 4]; return; }
    t -= 16384;
    if (t < 64) { w2c[t] = w2[t * 9 + 4]; }
}

__device__ __forceinline__ bf16x8 load_a_frag(const unsigned short* p, bool ok) {
    union U { uint4 u; bf16x8 v; } t;
    if (ok) t.u = *(const uint4*)p;
    else { t.u.x = 0u; t.u.y = 0u; t.u.z = 0u; t.u.w = 0u; }
    return t.v;
}

// ---------- kernel 3: implicit-GEMM conv + relu + row-sum ----------
// grid 896 = (b, y). block 256 = 4 waves; wave w owns N cols [w*64, w*64+64).
// M = 64 (56 valid x positions), K = 2304 = 9 taps * 256 ic, k-step 32.
__global__ __launch_bounds__(256) void k_conv(
    const unsigned short* __restrict__ xT,
    const unsigned short* __restrict__ Bp,
    const float* __restrict__ b0_0,
    float* __restrict__ partial) {
    __shared__ __align__(16) unsigned short lds_b[256 * 40];
    int blk = blockIdx.x;
    int b = blk / NW, y = blk % NW;
    int tid = threadIdx.x;
    int lane = tid & 63, wave = tid >> 6;
    int col = lane & 15, grp = lane >> 4;
    int koff = grp * 8;
    int nbase = wave * 64;

    f32x4 acc[4][4];
#pragma unroll
    for (int mt = 0; mt < 4; ++mt)
#pragma unroll
        for (int nt = 0; nt < 4; ++nt) {
            acc[mt][nt][0] = 0.f; acc[mt][nt][1] = 0.f;
            acc[mt][nt][2] = 0.f; acc[mt][nt][3] = 0.f;
        }

    const uint4* bsrc0 = (const uint4*)Bp + tid;
    int brow = tid >> 2;
    int bboff = (tid & 3) * 16;  // byte offset in LDS row

    for (int tap = 0; tap < 9; ++tap) {
        int ysrc = y + tap / 3 - 1;
        int dxo = tap % 3 - 1;
        if ((unsigned)ysrc >= (unsigned)NW) continue;  // whole-tap zero contribution (uniform)
        const unsigned short* aptr[4];
        bool aok[4];
#pragma unroll
        for (int mt = 0; mt < 4; ++mt) {
            int xs = mt * 16 + col + dxo;
            aok[mt] = ((unsigned)xs < (unsigned)NW);
            size_t pos = aok[mt] ? ((size_t)b * NHW + (size_t)ysrc * NW + xs) : 0;
            aptr[mt] = xT + pos * NC + koff;
        }
        for (int icb = 0; icb < 8; ++icb) {
            // stage B slab (256n x 32k bf16, 16KB) into padded LDS [n][40]
            const uint4* bs = bsrc0 + (size_t)(tap * 8 + icb) * 1024;
#pragma unroll
            for (int r = 0; r < 4; ++r) {
                uint4 v = bs[r * 256];
                *(uint4*)((char*)lds_b + (size_t)(brow + r * 64) * 80 + bboff) = v;
            }
            __syncthreads();
            bf16x8 af[4], bfr[4];
#pragma unroll
            for (int mt = 0; mt < 4; ++mt)
                af[mt] = load_a_frag(aptr[mt] + icb * 32, aok[mt]);
#pragma unroll
            for (int nt = 0; nt < 4; ++nt)
                bfr[nt] = *(const bf16x8*)((const char*)lds_b + (size_t)(nbase + nt * 16 + col) * 80 + koff * 2);
#pragma unroll
            for (int mt = 0; mt < 4; ++mt)
#pragma unroll
                for (int nt = 0; nt < 4; ++nt)
                    acc[mt][nt] = __builtin_amdgcn_mfma_f32_16x16x32_bf16(af[mt], bfr[nt], acc[mt][nt], 0, 0, 0);
            __syncthreads();
        }
    }

    // epilogue: bias + relu + sum over valid rows (m<56), reduce across lane groups
#pragma unroll
    for (int nt = 0; nt < 4; ++nt) {
        int n = nbase + nt * 16 + col;
        float bias = b0_0[n];
        float s = 0.f;
#pragma unroll
        for (int mt = 0; mt < 4; ++mt) {
#pragma unroll
            for (int j = 0; j < 4; ++j) {
                int m = mt * 16 + grp * 4 + j;
                float v = acc[mt][nt][j] + bias;
                v = v > 0.f ? v : 0.f;
                if (m < NW) s += v;
            }
        }
        s += __shfl_down(s, 32);
        s += __shfl_down(s, 16);
        if (grp == 0) partial[(size_t)blk * NC + n] = s;
    }
}

// ---------- kernel 4: tail (per-batch small chain) ----------
__global__ __launch_bounds__(256) void k_tail(
    const float* __restrict__ partial,
    const float* __restrict__ w01T, const float* __restrict__ fc1T,
    const float* __restrict__ w02T, const float* __restrict__ w03T,
    const float* __restrict__ w04T, const float* __restrict__ w1T,
    const float* __restrict__ w2c,
    const float* __restrict__ b0_1, const float* __restrict__ b0_2,
    const float* __restrict__ b0_3, const float* __restrict__ b0_4,
    const float* __restrict__ b1, const float* __restrict__ b2,
    const float* __restrict__ fc2_w, const float* __restrict__ fc2_b,
    const float* __restrict__ compat, const float* __restrict__ spatial_w,
    float* __restrict__ out) {
    __shared__ float fc[256], t2[256], t3[256], t4[256], red[256];
    __shared__ float f3s[64];
    __shared__ float vs_sh;
    int b = blockIdx.x, o = threadIdx.x;

    // f1c = mean over HW of relu(conv) : reduce 56 per-row partials
    float s = 0.f;
    const float* pp = partial + (size_t)b * 56 * 256 + o;
#pragma unroll 8
    for (int yy = 0; yy < 56; ++yy) s += pp[yy * 256];
    fc[o] = s * (1.f / 3136.f);
    __syncthreads();

    // f2 = relu(W01c @ f1c + b0_1); v_c = sigmoid(fc1 @ f1c); f_c = v_c * f2
    float a2 = 0.f, av = 0.f;
    for (int i = 0; i < 256; ++i) {
        float f = fc[i];
        a2 = fmaf(w01T[i * 256 + o], f, a2);
        av = fmaf(fc1T[i * 256 + o], f, av);
    }
    float f2v = fmaxf(a2 + b0_1[o], 0.f);
    float vc = 1.f / (1.f + expf(-av));
    t2[o] = vc * f2v;
    __syncthreads();

    // f3
    float a3 = 0.f;
    for (int i = 0; i < 256; ++i) a3 = fmaf(w02T[i * 256 + o], t2[i], a3);
    t3[o] = fmaxf(a3 + b0_2[o], 0.f);
    __syncthreads();

    // f4 and f3s
    float a4 = 0.f;
    for (int i = 0; i < 256; ++i) a4 = fmaf(w03T[i * 256 + o], t3[i], a4);
    t4[o] = fmaxf(a4 + b0_3[o], 0.f);
    if (o < 64) {
        float a5 = 0.f;
        for (int i = 0; i < 256; ++i) a5 = fmaf(w1T[i * 64 + o], t3[i], a5);
        f3s[o] = fmaxf(a5 + b1[o], 0.f);
    }
    __syncthreads();
    if (o < 64) red[o] = w2c[o] * f3s[o];
    __syncthreads();
    if (o == 0) {
        float u = 0.f;
        for (int i = 0; i < 64; ++i) u += red[i];
        u = fmaxf(u + b2[0], 0.f);   // v0s (relu)
        // CRF-RNN on 1x1 map: blur = q * G[1][1] = q * 0.25
        float c00 = compat[0], c01 = compat[1], c10 = compat[2], c11 = compat[3];
        float sw0 = spatial_w[0], sw1 = spatial_w[1];
        float q1 = 1.f / (1.f + expf(2.f * u));   // softmax([u,-u])[1]
        float q0 = 1.f - q1;
        for (int it = 0; it < 5; ++it) {
            float m0 = q0 * 0.25f * sw0;
            float m1 = q1 * 0.25f * sw1;
            float pw0 = c00 * m0 + c01 * m1;
            float pw1 = c10 * m0 + c11 * m1;
            float z0 = u - pw0, z1 = -u - pw1;
            q1 = 1.f / (1.f + expf(z0 - z1));
            q0 = 1.f - q1;
        }
        vs_sh = q1;
    }
    __syncthreads();
    t4[o] = vs_sh * t4[o];   // f_s
    __syncthreads();
    float a6 = 0.f;
    for (int i = 0; i < 256; ++i) a6 = fmaf(w04T[i * 256 + o], t4[i], a6);
    float fr = fmaxf(a6 + b0_4[o], 0.f);
    red[o] = fr * fc2_w[o];
    __syncthreads();
    for (int st = 128; st > 0; st >>= 1) {
        if (o < st) red[o] += red[o + st];
        __syncthreads();
    }
    if (o == 0) out[b] = 1.f / (1.f + expf(-(red[0] + fc2_b[0])));
}

extern "C" void kernel_launch(void* const* d_in, const int* in_sizes, int n_in,
                              void* d_out, int out_size, void* d_ws, size_t ws_size,
                              hipStream_t stream) {
    const float* x     = (const float*)d_in[0];
    const float* w0_0  = (const float*)d_in[1];
    const float* b0_0  = (const float*)d_in[2];
    const float* w0_1  = (const float*)d_in[3];
    const float* b0_1  = (const float*)d_in[4];
    const float* w0_2  = (const float*)d_in[5];
    const float* b0_2  = (const float*)d_in[6];
    const float* w0_3  = (const float*)d_in[7];
    const float* b0_3  = (const float*)d_in[8];
    const float* w0_4  = (const float*)d_in[9];
    const float* b0_4  = (const float*)d_in[10];
    const float* w1    = (const float*)d_in[11];
    const float* b1    = (const float*)d_in[12];
    const float* w2    = (const float*)d_in[13];
    const float* b2    = (const float*)d_in[14];
    const float* fc1_w = (const float*)d_in[15];
    const float* fc2_w = (const float*)d_in[16];
    const float* fc2_b = (const float*)d_in[17];
    const float* compat = (const float*)d_in[18];
    const float* sw     = (const float*)d_in[19];

    unsigned short* xT = (unsigned short*)d_ws;                  // 16*3136*256 bf16
    unsigned short* Bp = xT + (size_t)16 * 3136 * 256;           // 589824 bf16
    float* w01T = (float*)(Bp + 589824);
    float* w02T = w01T + 65536;
    float* w03T = w02T + 65536;
    float* w04T = w03T + 65536;
    float* fc1T = w04T + 65536;
    float* w1T  = fc1T + 65536;
    float* w2c  = w1T + 16384;
    float* partial = w2c + 64;                                   // 896*256 f32

    hipLaunchKernelGGL(k_repack_x, dim3(16 * 8 * 98), dim3(256), 0, stream, x, xT);
    hipLaunchKernelGGL(k_repack_w, dim3((933952 + 255) / 256), dim3(256), 0, stream,
                       w0_0, w0_1, w0_2, w0_3, w0_4, w1, w2, fc1_w,
                       Bp, w01T, w02T, w03T, w04T, fc1T, w1T, w2c);
    hipLaunchKernelGGL(k_conv, dim3(896), dim3(256), 0, stream, xT, Bp, b0_0, partial);
    hipLaunchKernelGGL(k_tail, dim3(16), dim3(256), 0, stream, partial,
                       w01T, fc1T, w02T, w03T, w04T, w1T, w2c,
                       b0_1, b0_2, b0_3, b0_4, b1, b2, fc2_w, fc2_b, compat, sw,
                       (float*)d_out);
}

// Round 2
// 328.386 us; speedup vs baseline: 1.0334x; 1.0334x over previous
//
#include <hip/hip_runtime.h>
#include <hip/hip_bf16.h>

typedef __bf16 bf16x8 __attribute__((ext_vector_type(8)));
typedef float f32x4 __attribute__((ext_vector_type(4)));

#define NB 16
#define NC 256
#define NHW 3136
#define NW 56

__device__ __forceinline__ unsigned short f2bf(float f) {
    union { float f; unsigned u; } v; v.f = f;
    unsigned r = v.u + 0x7FFFu + ((v.u >> 16) & 1u);
    return (unsigned short)(r >> 16);
}

// ---------- kernel 1: x NCHW f32 -> NHWC bf16 ----------
__global__ void k_repack_x(const float* __restrict__ x, unsigned short* __restrict__ xT) {
    __shared__ float tile[32][33];
    int bid = blockIdx.x;
    int hwb = bid % 98;
    int cb = (bid / 98) % 8;
    int b = bid / (98 * 8);
    int tid = threadIdx.x;
    {
        int c_l = tid >> 5, hw_l = tid & 31;
        const float* src = x + ((size_t)b * NC + (size_t)cb * 32) * NHW + hwb * 32;
#pragma unroll
        for (int r = 0; r < 4; ++r) {
            int c = c_l + r * 8;
            tile[c][hw_l] = src[(size_t)c * NHW + hw_l];
        }
    }
    __syncthreads();
    {
        int c2 = tid & 31, hw2 = tid >> 5;
        unsigned short* dst = xT + ((size_t)b * NHW + (size_t)hwb * 32) * NC + cb * 32;
#pragma unroll
        for (int r = 0; r < 4; ++r) {
            int hw = hw2 + r * 8;
            dst[(size_t)hw * NC + c2] = f2bf(tile[c2][hw]);
        }
    }
}

// ---------- kernel 2: weight repack ----------
// Bp[tap][icb][n][ic32] bf16  (9*8*256*32 = 589824)
// then transposed center-tap fp32 mats
__global__ void k_repack_w(const float* __restrict__ w0_0, const float* __restrict__ w0_1,
                           const float* __restrict__ w0_2, const float* __restrict__ w0_3,
                           const float* __restrict__ w0_4, const float* __restrict__ w1,
                           const float* __restrict__ w2, const float* __restrict__ fc1_w,
                           unsigned short* __restrict__ Bp, float* __restrict__ w01T,
                           float* __restrict__ w02T, float* __restrict__ w03T,
                           float* __restrict__ w04T, float* __restrict__ fc1T,
                           float* __restrict__ w1T, float* __restrict__ w2c) {
    int idx = blockIdx.x * 256 + threadIdx.x;
    if (idx < 589824) {
        int q = idx & 31;
        int n = (idx >> 5) & 255;
        int s = idx >> 13;            // 0..71 = tap*8 + icb
        int tap = s >> 3;
        int ic = (s & 7) * 32 + q;
        Bp[idx] = f2bf(w0_0[(size_t)n * 2304 + (size_t)ic * 9 + tap]);
        return;
    }
    int t = idx - 589824;
    if (t < 65536) { w01T[t] = w0_1[(size_t)(t & 255) * 2304 + (size_t)(t >> 8) * 9 + 4]; return; }
    t -= 65536;
    if (t < 65536) { w02T[t] = w0_2[(size_t)(t & 255) * 2304 + (size_t)(t >> 8) * 9 + 4]; return; }
    t -= 65536;
    if (t < 65536) { w03T[t] = w0_3[(size_t)(t & 255) * 2304 + (size_t)(t >> 8) * 9 + 4]; return; }
    t -= 65536;
    if (t < 65536) { w04T[t] = w0_4[(size_t)(t & 255) * 2304 + (size_t)(t >> 8) * 9 + 4]; return; }
    t -= 65536;
    if (t < 65536) { fc1T[t] = fc1_w[(size_t)(t & 255) * 256 + (t >> 8)]; return; }
    t -= 65536;
    if (t < 16384) { w1T[t] = w1[(size_t)(t & 63) * 2304 + (size_t)(t >> 6) * 9 + 4]; return; }
    t -= 16384;
    if (t < 64) { w2c[t] = w2[t * 9 + 4]; }
}

__device__ __forceinline__ bf16x8 load_a_frag(const unsigned short* p, bool ok) {
    union U { uint4 u; bf16x8 v; } t;
    if (ok) t.u = *(const uint4*)p;
    else { t.u.x = 0u; t.u.y = 0u; t.u.z = 0u; t.u.w = 0u; }
    return t.v;
}

// ---------- kernel 3: implicit-GEMM conv + relu + row-sum ----------
// grid 448 = (b, y-pair). block 256 = 4 waves; wave w owns N cols [w*64,+64),
// M = 128 (2 output rows of 56, each padded to 64). No LDS, no barriers:
// B frags read direct from L2-resident Bp (perfectly coalesced 1KB/instr),
// A frags direct from NHWC xT (L1/L2-hot).
__global__ __launch_bounds__(256, 2) void k_conv(
    const unsigned short* __restrict__ xT,
    const unsigned short* __restrict__ Bp,
    const float* __restrict__ b0_0,
    float* __restrict__ partial) {
    int blk = blockIdx.x;
    int b = blk / 28, y0 = (blk % 28) * 2;
    int tid = threadIdx.x;
    int lane = tid & 63, wave = tid >> 6;
    int col = lane & 15, grp = lane >> 4;
    int koff = grp * 8;
    int nbase = wave * 64;

    int nrow[4];
#pragma unroll
    for (int nt = 0; nt < 4; ++nt)
        nrow[nt] = (nbase + nt * 16 + col) * 32 + koff;

    f32x4 acc[8][4];
#pragma unroll
    for (int mt = 0; mt < 8; ++mt)
#pragma unroll
        for (int nt = 0; nt < 4; ++nt) {
            acc[mt][nt][0] = 0.f; acc[mt][nt][1] = 0.f;
            acc[mt][nt][2] = 0.f; acc[mt][nt][3] = 0.f;
        }

    for (int tap = 0; tap < 9; ++tap) {
        int dy = tap / 3 - 1, dx = tap % 3 - 1;
        int apos[8];
        bool ok[8];
#pragma unroll
        for (int mt = 0; mt < 8; ++mt) {
            int ysrc = y0 + (mt >> 2) + dy;
            int xs = (mt & 3) * 16 + col + dx;
            ok[mt] = ((unsigned)ysrc < (unsigned)NW) && ((unsigned)xs < (unsigned)NW);
            apos[mt] = ok[mt] ? (((b * NHW + ysrc * NW + xs) << 8) + koff) : koff;
        }
        const unsigned short* bbase = Bp + ((size_t)(tap * 8) << 13);
        for (int icb = 0; icb < 8; ++icb) {
            bf16x8 af[8], bfr[4];
#pragma unroll
            for (int mt = 0; mt < 8; ++mt)
                af[mt] = load_a_frag(xT + (size_t)apos[mt] + icb * 32, ok[mt]);
#pragma unroll
            for (int nt = 0; nt < 4; ++nt)
                bfr[nt] = *(const bf16x8*)(bbase + (((size_t)icb << 13) + nrow[nt]));
#pragma unroll
            for (int mt = 0; mt < 8; ++mt)
#pragma unroll
                for (int nt = 0; nt < 4; ++nt)
                    acc[mt][nt] = __builtin_amdgcn_mfma_f32_16x16x32_bf16(af[mt], bfr[nt], acc[mt][nt], 0, 0, 0);
        }
    }

    // epilogue: bias + relu + sum over valid x (<56) per output row
#pragma unroll
    for (int row = 0; row < 2; ++row) {
        int y = y0 + row;
#pragma unroll
        for (int nt = 0; nt < 4; ++nt) {
            int n = nbase + nt * 16 + col;
            float bias = b0_0[n];
            float s = 0.f;
#pragma unroll
            for (int mt4 = 0; mt4 < 4; ++mt4) {
#pragma unroll
                for (int j = 0; j < 4; ++j) {
                    int xp = mt4 * 16 + grp * 4 + j;
                    float v = acc[row * 4 + mt4][nt][j] + bias;
                    v = v > 0.f ? v : 0.f;
                    if (xp < NW) s += v;
                }
            }
            s += __shfl_down(s, 32);
            s += __shfl_down(s, 16);
            if (grp == 0) partial[((size_t)b * NW + y) * NC + n] = s;
        }
    }
}

// ---------- kernel 4: tail (per-batch small chain) ----------
__global__ __launch_bounds__(256) void k_tail(
    const float* __restrict__ partial,
    const float* __restrict__ w01T, const float* __restrict__ fc1T,
    const float* __restrict__ w02T, const float* __restrict__ w03T,
    const float* __restrict__ w04T, const float* __restrict__ w1T,
    const float* __restrict__ w2c,
    const float* __restrict__ b0_1, const float* __restrict__ b0_2,
    const float* __restrict__ b0_3, const float* __restrict__ b0_4,
    const float* __restrict__ b1, const float* __restrict__ b2,
    const float* __restrict__ fc2_w, const float* __restrict__ fc2_b,
    const float* __restrict__ compat, const float* __restrict__ spatial_w,
    float* __restrict__ out) {
    __shared__ float fc[256], t2[256], t3[256], t4[256], red[256];
    __shared__ float f3s[64];
    __shared__ float vs_sh;
    int b = blockIdx.x, o = threadIdx.x;

    float s = 0.f;
    const float* pp = partial + (size_t)b * 56 * 256 + o;
#pragma unroll 8
    for (int yy = 0; yy < 56; ++yy) s += pp[yy * 256];
    fc[o] = s * (1.f / 3136.f);
    __syncthreads();

    float a2 = 0.f, av = 0.f;
    for (int i = 0; i < 256; ++i) {
        float f = fc[i];
        a2 = fmaf(w01T[i * 256 + o], f, a2);
        av = fmaf(fc1T[i * 256 + o], f, av);
    }
    float f2v = fmaxf(a2 + b0_1[o], 0.f);
    float vc = 1.f / (1.f + expf(-av));
    t2[o] = vc * f2v;
    __syncthreads();

    float a3 = 0.f;
    for (int i = 0; i < 256; ++i) a3 = fmaf(w02T[i * 256 + o], t2[i], a3);
    t3[o] = fmaxf(a3 + b0_2[o], 0.f);
    __syncthreads();

    float a4 = 0.f;
    for (int i = 0; i < 256; ++i) a4 = fmaf(w03T[i * 256 + o], t3[i], a4);
    t4[o] = fmaxf(a4 + b0_3[o], 0.f);
    if (o < 64) {
        float a5 = 0.f;
        for (int i = 0; i < 256; ++i) a5 = fmaf(w1T[i * 64 + o], t3[i], a5);
        f3s[o] = fmaxf(a5 + b1[o], 0.f);
    }
    __syncthreads();
    if (o < 64) red[o] = w2c[o] * f3s[o];
    __syncthreads();
    if (o == 0) {
        float u = 0.f;
        for (int i = 0; i < 64; ++i) u += red[i];
        u = fmaxf(u + b2[0], 0.f);   // v0s (relu)
        float c00 = compat[0], c01 = compat[1], c10 = compat[2], c11 = compat[3];
        float sw0 = spatial_w[0], sw1 = spatial_w[1];
        float q1 = 1.f / (1.f + expf(2.f * u));   // softmax([u,-u])[1]
        float q0 = 1.f - q1;
        for (int it = 0; it < 5; ++it) {
            float m0 = q0 * 0.25f * sw0;
            float m1 = q1 * 0.25f * sw1;
            float pw0 = c00 * m0 + c01 * m1;
            float pw1 = c10 * m0 + c11 * m1;
            float z0 = u - pw0, z1 = -u - pw1;
            q1 = 1.f / (1.f + expf(z0 - z1));
            q0 = 1.f - q1;
        }
        vs_sh = q1;
    }
    __syncthreads();
    t4[o] = vs_sh * t4[o];   // f_s
    __syncthreads();
    float a6 = 0.f;
    for (int i = 0; i < 256; ++i) a6 = fmaf(w04T[i * 256 + o], t4[i], a6);
    float fr = fmaxf(a6 + b0_4[o], 0.f);
    red[o] = fr * fc2_w[o];
    __syncthreads();
    for (int st = 128; st > 0; st >>= 1) {
        if (o < st) red[o] += red[o + st];
        __syncthreads();
    }
    if (o == 0) out[b] = 1.f / (1.f + expf(-(red[0] + fc2_b[0])));
}

extern "C" void kernel_launch(void* const* d_in, const int* in_sizes, int n_in,
                              void* d_out, int out_size, void* d_ws, size_t ws_size,
                              hipStream_t stream) {
    const float* x     = (const float*)d_in[0];
    const float* w0_0  = (const float*)d_in[1];
    const float* b0_0  = (const float*)d_in[2];
    const float* w0_1  = (const float*)d_in[3];
    const float* b0_1  = (const float*)d_in[4];
    const float* w0_2  = (const float*)d_in[5];
    const float* b0_2  = (const float*)d_in[6];
    const float* w0_3  = (const float*)d_in[7];
    const float* b0_3  = (const float*)d_in[8];
    const float* w0_4  = (const float*)d_in[9];
    const float* b0_4  = (const float*)d_in[10];
    const float* w1    = (const float*)d_in[11];
    const float* b1    = (const float*)d_in[12];
    const float* w2    = (const float*)d_in[13];
    const float* b2    = (const float*)d_in[14];
    const float* fc1_w = (const float*)d_in[15];
    const float* fc2_w = (const float*)d_in[16];
    const float* fc2_b = (const float*)d_in[17];
    const float* compat = (const float*)d_in[18];
    const float* sw     = (const float*)d_in[19];

    unsigned short* xT = (unsigned short*)d_ws;                  // 16*3136*256 bf16
    unsigned short* Bp = xT + (size_t)16 * 3136 * 256;           // 589824 bf16
    float* w01T = (float*)(Bp + 589824);
    float* w02T = w01T + 65536;
    float* w03T = w02T + 65536;
    float* w04T = w03T + 65536;
    float* fc1T = w04T + 65536;
    float* w1T  = fc1T + 65536;
    float* w2c  = w1T + 16384;
    float* partial = w2c + 64;                                   // 896*256 f32

    hipLaunchKernelGGL(k_repack_x, dim3(16 * 8 * 98), dim3(256), 0, stream, x, xT);
    hipLaunchKernelGGL(k_repack_w, dim3((933952 + 255) / 256), dim3(256), 0, stream,
                       w0_0, w0_1, w0_2, w0_3, w0_4, w1, w2, fc1_w,
                       Bp, w01T, w02T, w03T, w04T, fc1T, w1T, w2c);
    hipLaunchKernelGGL(k_conv, dim3(448), dim3(256), 0, stream, xT, Bp, b0_0, partial);
    hipLaunchKernelGGL(k_tail, dim3(16), dim3(256), 0, stream, partial,
                       w01T, fc1T, w02T, w03T, w04T, w1T, w2c,
                       b0_1, b0_2, b0_3, b0_4, b1, b2, fc2_w, fc2_b, compat, sw,
                       (float*)d_out);
}

// Round 3
// 281.457 us; speedup vs baseline: 1.2057x; 1.1667x over previous
//
#include <hip/hip_runtime.h>
#include <hip/hip_bf16.h>

typedef __bf16 bf16x8 __attribute__((ext_vector_type(8)));
typedef float f32x4 __attribute__((ext_vector_type(4)));

#define NB 16
#define NC 256
#define NHW 3136
#define NW 56
#define PROW 58
#define PPLANE (58 * 58)

__device__ __forceinline__ unsigned short f2bf(float f) {
    union { float f; unsigned u; } v; v.f = f;
    unsigned r = v.u + 0x7FFFu + ((v.u >> 16) & 1u);
    return (unsigned short)(r >> 16);
}

// ---------- kernel 0: zero the 1-px halo of all 128 padded planes ----------
__global__ void k_zero_halo(unsigned short* __restrict__ xT) {
    int t = blockIdx.x * 256 + threadIdx.x;
    if (t >= 128 * 228) return;
    int plane = t / 228, h = t % 228;
    int row, xc;
    if (h < 58)       { row = 0;       xc = h; }
    else if (h < 116) { row = 57;      xc = h - 58; }
    else if (h < 172) { row = h - 115; xc = 0; }    // rows 1..56
    else              { row = h - 171; xc = 57; }   // rows 1..56
    size_t e = ((size_t)plane * PPLANE + (size_t)row * PROW + xc) * 32;
    uint4 z = {0u, 0u, 0u, 0u};
    *(uint4*)(xT + e)      = z;
    *(uint4*)(xT + e + 8)  = z;
    *(uint4*)(xT + e + 16) = z;
    *(uint4*)(xT + e + 24) = z;
}

// ---------- kernel 1: x NCHW f32 -> padded channel-blocked bf16 ----------
// xT[b][icb][ (y+1)*58 + (x+1) ][32ch]
__global__ void k_repack_x(const float* __restrict__ x, unsigned short* __restrict__ xT) {
    __shared__ float tile[32][33];
    int bid = blockIdx.x;
    int hwb = bid % 98;
    int cb = (bid / 98) % 8;
    int b = bid / (98 * 8);
    int tid = threadIdx.x;
    {
        int c_l = tid >> 5, hw_l = tid & 31;
        const float* src = x + ((size_t)b * NC + (size_t)cb * 32) * NHW + hwb * 32;
#pragma unroll
        for (int r = 0; r < 4; ++r) {
            int c = c_l + r * 8;
            tile[c][hw_l] = src[(size_t)c * NHW + hw_l];
        }
    }
    __syncthreads();
    {
        int qd = tid & 7, hw2 = tid >> 3;        // 8 channel-quads x 32 hw
        int hw = hwb * 32 + hw2;
        int y = hw / 56, xp = hw - y * 56;
        unsigned short* dst = xT + ((size_t)(b * 8 + cb) * PPLANE +
                                    (size_t)(y + 1) * PROW + (xp + 1)) * 32 + qd * 4;
        ushort4 v;
        v.x = f2bf(tile[qd * 4 + 0][hw2]);
        v.y = f2bf(tile[qd * 4 + 1][hw2]);
        v.z = f2bf(tile[qd * 4 + 2][hw2]);
        v.w = f2bf(tile[qd * 4 + 3][hw2]);
        *(ushort4*)dst = v;
    }
}

// ---------- kernel 2: weight repack ----------
// Bp[tap][icb][n][ic32] bf16  (9*8*256*32 = 589824) + transposed center-tap fp32 mats
__global__ void k_repack_w(const float* __restrict__ w0_0, const float* __restrict__ w0_1,
                           const float* __restrict__ w0_2, const float* __restrict__ w0_3,
                           const float* __restrict__ w0_4, const float* __restrict__ w1,
                           const float* __restrict__ w2, const float* __restrict__ fc1_w,
                           unsigned short* __restrict__ Bp, float* __restrict__ w01T,
                           float* __restrict__ w02T, float* __restrict__ w03T,
                           float* __restrict__ w04T, float* __restrict__ fc1T,
                           float* __restrict__ w1T, float* __restrict__ w2c) {
    int idx = blockIdx.x * 256 + threadIdx.x;
    if (idx < 589824) {
        int q = idx & 31;
        int n = (idx >> 5) & 255;
        int s = idx >> 13;            // 0..71 = tap*8 + icb
        int tap = s >> 3;
        int ic = (s & 7) * 32 + q;
        Bp[idx] = f2bf(w0_0[(size_t)n * 2304 + (size_t)ic * 9 + tap]);
        return;
    }
    int t = idx - 589824;
    if (t < 65536) { w01T[t] = w0_1[(size_t)(t & 255) * 2304 + (size_t)(t >> 8) * 9 + 4]; return; }
    t -= 65536;
    if (t < 65536) { w02T[t] = w0_2[(size_t)(t & 255) * 2304 + (size_t)(t >> 8) * 9 + 4]; return; }
    t -= 65536;
    if (t < 65536) { w03T[t] = w0_3[(size_t)(t & 255) * 2304 + (size_t)(t >> 8) * 9 + 4]; return; }
    t -= 65536;
    if (t < 65536) { w04T[t] = w0_4[(size_t)(t & 255) * 2304 + (size_t)(t >> 8) * 9 + 4]; return; }
    t -= 65536;
    if (t < 65536) { fc1T[t] = fc1_w[(size_t)(t & 255) * 256 + (t >> 8)]; return; }
    t -= 65536;
    if (t < 16384) { w1T[t] = w1[(size_t)(t & 63) * 2304 + (size_t)(t >> 6) * 9 + 4]; return; }
    t -= 16384;
    if (t < 64) { w2c[t] = w2[t * 9 + 4]; }
}

// ---------- kernel 3: implicit-GEMM conv + relu + sum ----------
// grid 448 = b*28 + pt; block 256 = 4 waves, wave owns N cols [w*64,+64).
// M = 112 flat pixels (pt*112 .. +112), K = 2304. All loads 1KB-coalesced,
// halo removes all masks; A frag addr = uniform plane + fixed lane offset + imm.
__global__ __launch_bounds__(256, 2) void k_conv(
    const unsigned short* __restrict__ xT,
    const unsigned short* __restrict__ Bp,
    const float* __restrict__ b0_0,
    float* __restrict__ partial) {
    int blk = blockIdx.x;
    int b = blk / 28, pt = blk % 28;
    int tid = threadIdx.x;
    int lane = tid & 63, wave = tid >> 6;
    int col = lane & 15, grp = lane >> 4;
    int nbase = wave * 64;

    int aoff[7];
#pragma unroll
    for (int mt = 0; mt < 7; ++mt) {
        int q = mt * 16 + col;            // 0..111
        int py0 = q >= 56 ? 1 : 0;
        int px = q - 56 * py0;
        int prow = pt * 2 + py0;
        aoff[mt] = (((prow + 1) * PROW + px + 1) * 32 + grp * 8) * 2;  // bytes
    }
    int boff[4];
#pragma unroll
    for (int nt = 0; nt < 4; ++nt)
        boff[nt] = ((nbase + nt * 16 + col) * 32 + grp * 8) * 2;       // bytes

    f32x4 acc[7][4];
#pragma unroll
    for (int mt = 0; mt < 7; ++mt)
#pragma unroll
        for (int nt = 0; nt < 4; ++nt) {
            acc[mt][nt][0] = 0.f; acc[mt][nt][1] = 0.f;
            acc[mt][nt][2] = 0.f; acc[mt][nt][3] = 0.f;
        }

    for (int icb = 0; icb < 8; ++icb) {
        const char* aplane = (const char*)(xT + (size_t)(b * 8 + icb) * PPLANE * 32);
#pragma unroll
        for (int dy = -1; dy <= 1; ++dy) {
#pragma unroll
            for (int dx = -1; dx <= 1; ++dx) {
                int tap = (dy + 1) * 3 + (dx + 1);
                const char* bplane = (const char*)(Bp + ((size_t)(tap * 8 + icb) << 13));
                bf16x8 af[7], bfr[4];
#pragma unroll
                for (int nt = 0; nt < 4; ++nt)
                    bfr[nt] = *(const bf16x8*)(bplane + boff[nt]);
#pragma unroll
                for (int mt = 0; mt < 7; ++mt)
                    af[mt] = *(const bf16x8*)(aplane + (aoff[mt] + (dy * PROW + dx) * 64));
#pragma unroll
                for (int mt = 0; mt < 7; ++mt)
#pragma unroll
                    for (int nt = 0; nt < 4; ++nt)
                        acc[mt][nt] = __builtin_amdgcn_mfma_f32_16x16x32_bf16(af[mt], bfr[nt], acc[mt][nt], 0, 0, 0);
            }
        }
    }

    // epilogue: bias + relu + sum over all 112 (all-valid) pixels
#pragma unroll
    for (int nt = 0; nt < 4; ++nt) {
        int n = nbase + nt * 16 + col;
        float bias = b0_0[n];
        float s = 0.f;
#pragma unroll
        for (int mt = 0; mt < 7; ++mt)
#pragma unroll
            for (int j = 0; j < 4; ++j)
                s += fmaxf(acc[mt][nt][j] + bias, 0.f);
        s += __shfl_down(s, 32);
        s += __shfl_down(s, 16);
        if (grp == 0) partial[(size_t)blk * NC + n] = s;
    }
}

// ---------- kernel 4: tail (per-batch small chain) ----------
__global__ __launch_bounds__(256) void k_tail(
    const float* __restrict__ partial,
    const float* __restrict__ w01T, const float* __restrict__ fc1T,
    const float* __restrict__ w02T, const float* __restrict__ w03T,
    const float* __restrict__ w04T, const float* __restrict__ w1T,
    const float* __restrict__ w2c,
    const float* __restrict__ b0_1, const float* __restrict__ b0_2,
    const float* __restrict__ b0_3, const float* __restrict__ b0_4,
    const float* __restrict__ b1, const float* __restrict__ b2,
    const float* __restrict__ fc2_w, const float* __restrict__ fc2_b,
    const float* __restrict__ compat, const float* __restrict__ spatial_w,
    float* __restrict__ out) {
    __shared__ float fc[256], t2[256], t3[256], t4[256], red[256];
    __shared__ float f3s[64];
    __shared__ float vs_sh;
    int b = blockIdx.x, o = threadIdx.x;

    float s = 0.f;
    const float* pp = partial + (size_t)b * 28 * 256 + o;
#pragma unroll 7
    for (int yy = 0; yy < 28; ++yy) s += pp[yy * 256];
    fc[o] = s * (1.f / 3136.f);
    __syncthreads();

    float a2 = 0.f, av = 0.f;
    for (int i = 0; i < 256; ++i) {
        float f = fc[i];
        a2 = fmaf(w01T[i * 256 + o], f, a2);
        av = fmaf(fc1T[i * 256 + o], f, av);
    }
    float f2v = fmaxf(a2 + b0_1[o], 0.f);
    float vc = 1.f / (1.f + expf(-av));
    t2[o] = vc * f2v;
    __syncthreads();

    float a3 = 0.f;
    for (int i = 0; i < 256; ++i) a3 = fmaf(w02T[i * 256 + o], t2[i], a3);
    t3[o] = fmaxf(a3 + b0_2[o], 0.f);
    __syncthreads();

    float a4 = 0.f;
    for (int i = 0; i < 256; ++i) a4 = fmaf(w03T[i * 256 + o], t3[i], a4);
    t4[o] = fmaxf(a4 + b0_3[o], 0.f);
    if (o < 64) {
        float a5 = 0.f;
        for (int i = 0; i < 256; ++i) a5 = fmaf(w1T[i * 64 + o], t3[i], a5);
        f3s[o] = fmaxf(a5 + b1[o], 0.f);
    }
    __syncthreads();
    if (o < 64) red[o] = w2c[o] * f3s[o];
    __syncthreads();
    if (o == 0) {
        float u = 0.f;
        for (int i = 0; i < 64; ++i) u += red[i];
        u = fmaxf(u + b2[0], 0.f);   // v0s (relu)
        float c00 = compat[0], c01 = compat[1], c10 = compat[2], c11 = compat[3];
        float sw0 = spatial_w[0], sw1 = spatial_w[1];
        float q1 = 1.f / (1.f + expf(2.f * u));   // softmax([u,-u])[1]
        float q0 = 1.f - q1;
        for (int it = 0; it < 5; ++it) {
            float m0 = q0 * 0.25f * sw0;
            float m1 = q1 * 0.25f * sw1;
            float pw0 = c00 * m0 + c01 * m1;
            float pw1 = c10 * m0 + c11 * m1;
            float z0 = u - pw0, z1 = -u - pw1;
            q1 = 1.f / (1.f + expf(z0 - z1));
            q0 = 1.f - q1;
        }
        vs_sh = q1;
    }
    __syncthreads();
    t4[o] = vs_sh * t4[o];   // f_s
    __syncthreads();
    float a6 = 0.f;
    for (int i = 0; i < 256; ++i) a6 = fmaf(w04T[i * 256 + o], t4[i], a6);
    float fr = fmaxf(a6 + b0_4[o], 0.f);
    red[o] = fr * fc2_w[o];
    __syncthreads();
    for (int st = 128; st > 0; st >>= 1) {
        if (o < st) red[o] += red[o + st];
        __syncthreads();
    }
    if (o == 0) out[b] = 1.f / (1.f + expf(-(red[0] + fc2_b[0])));
}

extern "C" void kernel_launch(void* const* d_in, const int* in_sizes, int n_in,
                              void* d_out, int out_size, void* d_ws, size_t ws_size,
                              hipStream_t stream) {
    const float* x     = (const float*)d_in[0];
    const float* w0_0  = (const float*)d_in[1];
    const float* b0_0  = (const float*)d_in[2];
    const float* w0_1  = (const float*)d_in[3];
    const float* b0_1  = (const float*)d_in[4];
    const float* w0_2  = (const float*)d_in[5];
    const float* b0_2  = (const float*)d_in[6];
    const float* w0_3  = (const float*)d_in[7];
    const float* b0_3  = (const float*)d_in[8];
    const float* w0_4  = (const float*)d_in[9];
    const float* b0_4  = (const float*)d_in[10];
    const float* w1    = (const float*)d_in[11];
    const float* b1    = (const float*)d_in[12];
    const float* w2    = (const float*)d_in[13];
    const float* b2    = (const float*)d_in[14];
    const float* fc1_w = (const float*)d_in[15];
    const float* fc2_w = (const float*)d_in[16];
    const float* fc2_b = (const float*)d_in[17];
    const float* compat = (const float*)d_in[18];
    const float* sw     = (const float*)d_in[19];

    unsigned short* xT = (unsigned short*)d_ws;                       // 128 planes * 3364 px * 32ch bf16
    unsigned short* Bp = xT + (size_t)128 * PPLANE * 32;              // 589824 bf16
    float* w01T = (float*)(Bp + 589824);
    float* w02T = w01T + 65536;
    float* w03T = w02T + 65536;
    float* w04T = w03T + 65536;
    float* fc1T = w04T + 65536;
    float* w1T  = fc1T + 65536;
    float* w2c  = w1T + 16384;
    float* partial = w2c + 64;                                        // 448*256 f32

    hipLaunchKernelGGL(k_zero_halo, dim3((128 * 228 + 255) / 256), dim3(256), 0, stream, xT);
    hipLaunchKernelGGL(k_repack_x, dim3(16 * 8 * 98), dim3(256), 0, stream, x, xT);
    hipLaunchKernelGGL(k_repack_w, dim3((933952 + 255) / 256), dim3(256), 0, stream,
                       w0_0, w0_1, w0_2, w0_3, w0_4, w1, w2, fc1_w,
                       Bp, w01T, w02T, w03T, w04T, fc1T, w1T, w2c);
    hipLaunchKernelGGL(k_conv, dim3(448), dim3(256), 0, stream, xT, Bp, b0_0, partial);
    hipLaunchKernelGGL(k_tail, dim3(16), dim3(256), 0, stream, partial,
                       w01T, fc1T, w02T, w03T, w04T, w1T, w2c,
                       b0_1, b0_2, b0_3, b0_4, b1, b2, fc2_w, fc2_b, compat, sw,
                       (float*)d_out);
}

// Round 4
// 213.136 us; speedup vs baseline: 1.5922x; 1.3206x over previous
//
#include <hip/hip_runtime.h>
#include <hip/hip_bf16.h>

typedef __bf16 bf16x8 __attribute__((ext_vector_type(8)));
typedef float f32x4 __attribute__((ext_vector_type(4)));

#define NB 16
#define NC 256
#define NHW 3136
#define NW 56
#define PROW 58
#define PPLANE (58 * 58)

__device__ __forceinline__ unsigned short f2bf(float f) {
    union { float f; unsigned u; } v; v.f = f;
    unsigned r = v.u + 0x7FFFu + ((v.u >> 16) & 1u);
    return (unsigned short)(r >> 16);
}

__device__ __forceinline__ void gload_lds16(const void* g, void* l) {
    __builtin_amdgcn_global_load_lds((const __attribute__((address_space(1))) void*)g,
                                     (__attribute__((address_space(3))) void*)l, 16, 0, 0);
}

// ---------- kernel 0: zero the 1-px halo of all 128 padded planes ----------
__global__ void k_zero_halo(unsigned short* __restrict__ xT) {
    int t = blockIdx.x * 256 + threadIdx.x;
    if (t >= 128 * 228) return;
    int plane = t / 228, h = t % 228;
    int row, xc;
    if (h < 58)       { row = 0;       xc = h; }
    else if (h < 116) { row = 57;      xc = h - 58; }
    else if (h < 172) { row = h - 115; xc = 0; }
    else              { row = h - 171; xc = 57; }
    size_t e = ((size_t)plane * PPLANE + (size_t)row * PROW + xc) * 32;
    uint4 z = {0u, 0u, 0u, 0u};
    *(uint4*)(xT + e)      = z;
    *(uint4*)(xT + e + 8)  = z;
    *(uint4*)(xT + e + 16) = z;
    *(uint4*)(xT + e + 24) = z;
}

// ---------- kernel 1: x NCHW f32 -> padded channel-blocked bf16 ----------
__global__ void k_repack_x(const float* __restrict__ x, unsigned short* __restrict__ xT) {
    __shared__ float tile[32][33];
    int bid = blockIdx.x;
    int hwb = bid % 98;
    int cb = (bid / 98) % 8;
    int b = bid / (98 * 8);
    int tid = threadIdx.x;
    {
        int c_l = tid >> 5, hw_l = tid & 31;
        const float* src = x + ((size_t)b * NC + (size_t)cb * 32) * NHW + hwb * 32;
#pragma unroll
        for (int r = 0; r < 4; ++r) {
            int c = c_l + r * 8;
            tile[c][hw_l] = src[(size_t)c * NHW + hw_l];
        }
    }
    __syncthreads();
    {
        int qd = tid & 7, hw2 = tid >> 3;
        int hw = hwb * 32 + hw2;
        int y = hw / 56, xp = hw - y * 56;
        unsigned short* dst = xT + ((size_t)(b * 8 + cb) * PPLANE +
                                    (size_t)(y + 1) * PROW + (xp + 1)) * 32 + qd * 4;
        ushort4 v;
        v.x = f2bf(tile[qd * 4 + 0][hw2]);
        v.y = f2bf(tile[qd * 4 + 1][hw2]);
        v.z = f2bf(tile[qd * 4 + 2][hw2]);
        v.w = f2bf(tile[qd * 4 + 3][hw2]);
        *(ushort4*)dst = v;
    }
}

// ---------- kernel 2: weight repack (Bp dense + LDS-transposed tail mats) ----------
__global__ void k_repack_w(const float* __restrict__ w0_0, const float* __restrict__ w0_1,
                           const float* __restrict__ w0_2, const float* __restrict__ w0_3,
                           const float* __restrict__ w0_4, const float* __restrict__ w1,
                           const float* __restrict__ w2, const float* __restrict__ fc1_w,
                           unsigned short* __restrict__ Bp, float* __restrict__ w01T,
                           float* __restrict__ w02T, float* __restrict__ w03T,
                           float* __restrict__ w04T, float* __restrict__ fc1T,
                           float* __restrict__ w1T, float* __restrict__ w2c) {
    int bid = blockIdx.x, tid = threadIdx.x;
    if (bid < 2304) {
        int idx = bid * 256 + tid;
        int q = idx & 31;
        int n = (idx >> 5) & 255;
        int s = idx >> 13;
        int tap = s >> 3;
        int ic = (s & 7) * 32 + q;
        Bp[idx] = f2bf(w0_0[(size_t)n * 2304 + (size_t)ic * 9 + tap]);
        return;
    }
    int tb = bid - 2304;
    __shared__ float tile[64][65];
    if (tb < 84) {
        const float* src; float* dst;
        int sstr, estr, off, OD, o0, i0;
        if (tb < 80) {
            int arr = tb >> 4, t16 = tb & 15;
            o0 = (t16 >> 2) * 64; i0 = (t16 & 3) * 64; OD = 256;
            sstr = 2304; estr = 9; off = 4;
            switch (arr) {
                case 0: src = w0_1; dst = w01T; break;
                case 1: src = w0_2; dst = w02T; break;
                case 2: src = w0_3; dst = w03T; break;
                case 3: src = w0_4; dst = w04T; break;
                default: src = fc1_w; dst = fc1T; sstr = 256; estr = 1; off = 0; break;
            }
        } else {
            int t4i = tb - 80; o0 = 0; i0 = t4i * 64; OD = 64;
            sstr = 2304; estr = 9; off = 4;
            src = w1; dst = w1T;
        }
        int i1 = tid & 63, o4 = tid >> 6;
#pragma unroll
        for (int p = 0; p < 16; ++p) {
            int oo = p * 4 + o4;
            tile[oo][i1] = src[(size_t)(o0 + oo) * sstr + (size_t)(i0 + i1) * estr + off];
        }
        __syncthreads();
        int o1 = tid & 63, i4 = tid >> 6;
#pragma unroll
        for (int p = 0; p < 16; ++p) {
            int ii = p * 4 + i4;
            dst[(size_t)(i0 + ii) * OD + o0 + o1] = tile[o1][ii];
        }
    } else {
        if (tid < 64) w2c[tid] = w2[tid * 9 + 4];
    }
}

// ---------- kernel 3: implicit-GEMM conv + relu + sum, LDS-A double-buffered ----------
// grid 448 = b*28 + pt; 4 waves, wave owns 64 N cols. M=112 flat px, K=2304.
// A staged per-icb via global_load_lds (swizzled source, linear LDS dest).
__global__ __launch_bounds__(256, 2) void k_conv(
    const unsigned short* __restrict__ xT,
    const unsigned short* __restrict__ Bp,
    const float* __restrict__ b0_0,
    float* __restrict__ partial) {
    __shared__ __align__(16) char alds[2][16384];   // [buf][4 rows][64 px][64B]
    int blk = blockIdx.x;
    int b = blk / 28, pt = blk % 28;
    int tid = threadIdx.x;
    int lane = tid & 63, wave = tid >> 6;
    int col = lane & 15, grp = lane >> 4;
    int nbase = wave * 64;

    // staging: per-lane swizzled global pixel offset (bytes)
    int swz = (lane & 3) ^ ((lane >> 3) & 3);
    int pixoff = ((lane >> 2) << 6) + (swz << 4);
    const char* xbytes = (const char*)xT;
    size_t stage_row = (size_t)(pt * 2 + wave) * (PROW * 64);

    // read-side LDS offsets: p_[mt][dx+1] (+ (dy+1)*4096 immediate per tap)
    int p_[7][3];
#pragma unroll
    for (int mt = 0; mt < 7; ++mt) {
        int q = mt * 16 + col;
        int r = q >= 56 ? 1 : 0;
        int x = q - 56 * r;
#pragma unroll
        for (int dxi = 0; dxi < 3; ++dxi) {
            int ppx = x + dxi;
            int slot = grp ^ ((ppx >> 1) & 3);
            p_[mt][dxi] = r * 4096 + ppx * 64 + slot * 16;
        }
    }
    int boff[4];
#pragma unroll
    for (int nt = 0; nt < 4; ++nt)
        boff[nt] = ((nbase + nt * 16 + col) * 32 + grp * 8) * 2;

    f32x4 acc[7][4];
#pragma unroll
    for (int mt = 0; mt < 7; ++mt)
#pragma unroll
        for (int nt = 0; nt < 4; ++nt) {
            acc[mt][nt][0] = 0.f; acc[mt][nt][1] = 0.f;
            acc[mt][nt][2] = 0.f; acc[mt][nt][3] = 0.f;
        }

    // prologue: stage icb=0 into buf0
    {
        const char* g0 = xbytes + (size_t)(b * 8) * (PPLANE * 64) + stage_row + pixoff;
        char* l0 = &alds[0][wave * 4096];
#pragma unroll
        for (int j = 0; j < 4; ++j)
            gload_lds16(g0 + j * 1024, l0 + j * 1024);
    }
    __syncthreads();

    for (int icb = 0; icb < 8; ++icb) {
        int cur = icb & 1;
        if (icb < 7) {
            const char* g = xbytes + (size_t)(b * 8 + icb + 1) * (PPLANE * 64) + stage_row + pixoff;
            char* l = &alds[cur ^ 1][wave * 4096];
#pragma unroll
            for (int j = 0; j < 4; ++j)
                gload_lds16(g + j * 1024, l + j * 1024);
        }
        const char* abuf = alds[cur];
#pragma unroll
        for (int dy = -1; dy <= 1; ++dy) {
#pragma unroll
            for (int dx = -1; dx <= 1; ++dx) {
                int tap = (dy + 1) * 3 + (dx + 1);
                const char* bplane = (const char*)(Bp + ((size_t)(tap * 8 + icb) << 13));
                bf16x8 af[7], bfr[4];
#pragma unroll
                for (int nt = 0; nt < 4; ++nt)
                    bfr[nt] = *(const bf16x8*)(bplane + boff[nt]);
#pragma unroll
                for (int mt = 0; mt < 7; ++mt)
                    af[mt] = *(const bf16x8*)(abuf + (p_[mt][dx + 1] + (dy + 1) * 4096));
#pragma unroll
                for (int mt = 0; mt < 7; ++mt)
#pragma unroll
                    for (int nt = 0; nt < 4; ++nt)
                        acc[mt][nt] = __builtin_amdgcn_mfma_f32_16x16x32_bf16(af[mt], bfr[nt], acc[mt][nt], 0, 0, 0);
            }
        }
        __syncthreads();
    }

    // epilogue: bias + relu + sum over all 112 pixels
#pragma unroll
    for (int nt = 0; nt < 4; ++nt) {
        int n = nbase + nt * 16 + col;
        float bias = b0_0[n];
        float s = 0.f;
#pragma unroll
        for (int mt = 0; mt < 7; ++mt)
#pragma unroll
            for (int j = 0; j < 4; ++j)
                s += fmaxf(acc[mt][nt][j] + bias, 0.f);
        s += __shfl_down(s, 32);
        s += __shfl_down(s, 16);
        if (grp == 0) partial[(size_t)blk * NC + n] = s;
    }
}

// ---------- kernel 4: tail, 1024 threads, 4-way K-split matvecs ----------
__global__ __launch_bounds__(1024) void k_tail(
    const float* __restrict__ partial,
    const float* __restrict__ w01T, const float* __restrict__ fc1T,
    const float* __restrict__ w02T, const float* __restrict__ w03T,
    const float* __restrict__ w04T, const float* __restrict__ w1T,
    const float* __restrict__ w2c,
    const float* __restrict__ b0_1, const float* __restrict__ b0_2,
    const float* __restrict__ b0_3, const float* __restrict__ b0_4,
    const float* __restrict__ b1, const float* __restrict__ b2,
    const float* __restrict__ fc2_w, const float* __restrict__ fc2_b,
    const float* __restrict__ compat, const float* __restrict__ spatial_w,
    float* __restrict__ out) {
    __shared__ float fc[256], t2[256], t3[256], t4[256];
    __shared__ float rA[4][256], rB[4][256];
    __shared__ float red64[64];
    __shared__ float vs_sh;
    int b = blockIdx.x, tid = threadIdx.x;
    int o = tid & 255, seg = tid >> 8;
    int i0 = seg * 64;

    // f1c mean
    {
        float s = 0.f;
        const float* pp = partial + (size_t)b * 28 * 256 + o;
#pragma unroll
        for (int r = seg * 7; r < seg * 7 + 7; ++r) s += pp[r * 256];
        rA[seg][o] = s;
    }
    __syncthreads();
    if (seg == 0) fc[o] = (rA[0][o] + rA[1][o] + rA[2][o] + rA[3][o]) * (1.f / 3136.f);
    __syncthreads();

    // stage2: f2 & v_c
    {
        float a2 = 0.f, av = 0.f;
        for (int i = i0; i < i0 + 64; ++i) {
            float fi = fc[i];
            a2 = fmaf(w01T[i * 256 + o], fi, a2);
            av = fmaf(fc1T[i * 256 + o], fi, av);
        }
        rA[seg][o] = a2; rB[seg][o] = av;
    }
    __syncthreads();
    if (seg == 0) {
        float A = rA[0][o] + rA[1][o] + rA[2][o] + rA[3][o];
        float V = rB[0][o] + rB[1][o] + rB[2][o] + rB[3][o];
        t2[o] = fmaxf(A + b0_1[o], 0.f) / (1.f + expf(-V));
    }
    __syncthreads();

    // stage3: f3
    {
        float a3 = 0.f;
        for (int i = i0; i < i0 + 64; ++i) a3 = fmaf(w02T[i * 256 + o], t2[i], a3);
        rA[seg][o] = a3;
    }
    __syncthreads();
    if (seg == 0) t3[o] = fmaxf(rA[0][o] + rA[1][o] + rA[2][o] + rA[3][o] + b0_2[o], 0.f);
    __syncthreads();

    // stage4: f4 (w03T) + f3s (w1T, 16-way split)
    {
        float a4 = 0.f;
        for (int i = i0; i < i0 + 64; ++i) a4 = fmaf(w03T[i * 256 + o], t3[i], a4);
        rA[seg][o] = a4;
        int o64 = tid & 63, s16 = tid >> 6;
        float a5 = 0.f;
        for (int i = s16 * 16; i < s16 * 16 + 16; ++i) a5 = fmaf(w1T[i * 64 + o64], t3[i], a5);
        ((float*)rB)[s16 * 64 + o64] = a5;
    }
    __syncthreads();
    if (seg == 0) t4[o] = fmaxf(rA[0][o] + rA[1][o] + rA[2][o] + rA[3][o] + b0_3[o], 0.f);
    if (tid < 64) {
        float a5 = 0.f;
        const float* rb = (const float*)rB;
#pragma unroll
        for (int j = 0; j < 16; ++j) a5 += rb[j * 64 + tid];
        float v = fmaxf(a5 + b1[tid], 0.f);
        red64[tid] = v * w2c[tid];
    }
    __syncthreads();
    if (tid == 0) {
        float u = 0.f;
        for (int i = 0; i < 64; ++i) u += red64[i];
        u = fmaxf(u + b2[0], 0.f);
        float c00 = compat[0], c01 = compat[1], c10 = compat[2], c11 = compat[3];
        float sw0 = spatial_w[0], sw1 = spatial_w[1];
        float q1 = 1.f / (1.f + expf(2.f * u));
        float q0 = 1.f - q1;
        for (int it = 0; it < 5; ++it) {
            float m0 = q0 * 0.25f * sw0;
            float m1 = q1 * 0.25f * sw1;
            float pw0 = c00 * m0 + c01 * m1;
            float pw1 = c10 * m0 + c11 * m1;
            float z0 = u - pw0, z1 = -u - pw1;
            q1 = 1.f / (1.f + expf(z0 - z1));
            q0 = 1.f - q1;
        }
        vs_sh = q1;
    }
    __syncthreads();

    // stage5: f_r via linearity (a6 = vs * sum w04T.t4), then fc2
    {
        float a6 = 0.f;
        for (int i = i0; i < i0 + 64; ++i) a6 = fmaf(w04T[i * 256 + o], t4[i], a6);
        rA[seg][o] = a6;
    }
    __syncthreads();
    if (seg == 0) {
        float A = rA[0][o] + rA[1][o] + rA[2][o] + rA[3][o];
        float fr = fmaxf(vs_sh * A + b0_4[o], 0.f);
        rB[0][o] = fr * fc2_w[o];
    }
    __syncthreads();
    if (tid < 128) rB[0][tid] += rB[0][tid + 128];
    __syncthreads();
    if (tid < 64) rB[0][tid] += rB[0][tid + 64];
    __syncthreads();
    if (tid == 0) {
        float t = 0.f;
        for (int i = 0; i < 64; ++i) t += rB[0][i];
        out[b] = 1.f / (1.f + expf(-(t + fc2_b[0])));
    }
}

extern "C" void kernel_launch(void* const* d_in, const int* in_sizes, int n_in,
                              void* d_out, int out_size, void* d_ws, size_t ws_size,
                              hipStream_t stream) {
    const float* x     = (const float*)d_in[0];
    const float* w0_0  = (const float*)d_in[1];
    const float* b0_0  = (const float*)d_in[2];
    const float* w0_1  = (const float*)d_in[3];
    const float* b0_1  = (const float*)d_in[4];
    const float* w0_2  = (const float*)d_in[5];
    const float* b0_2  = (const float*)d_in[6];
    const float* w0_3  = (const float*)d_in[7];
    const float* b0_3  = (const float*)d_in[8];
    const float* w0_4  = (const float*)d_in[9];
    const float* b0_4  = (const float*)d_in[10];
    const float* w1    = (const float*)d_in[11];
    const float* b1    = (const float*)d_in[12];
    const float* w2    = (const float*)d_in[13];
    const float* b2    = (const float*)d_in[14];
    const float* fc1_w = (const float*)d_in[15];
    const float* fc2_w = (const float*)d_in[16];
    const float* fc2_b = (const float*)d_in[17];
    const float* compat = (const float*)d_in[18];
    const float* sw     = (const float*)d_in[19];

    unsigned short* xT = (unsigned short*)d_ws;
    unsigned short* Bp = xT + (size_t)128 * PPLANE * 32;
    float* w01T = (float*)(Bp + 589824);
    float* w02T = w01T + 65536;
    float* w03T = w02T + 65536;
    float* w04T = w03T + 65536;
    float* fc1T = w04T + 65536;
    float* w1T  = fc1T + 65536;
    float* w2c  = w1T + 16384;
    float* partial = w2c + 64;

    hipLaunchKernelGGL(k_zero_halo, dim3((128 * 228 + 255) / 256), dim3(256), 0, stream, xT);
    hipLaunchKernelGGL(k_repack_x, dim3(16 * 8 * 98), dim3(256), 0, stream, x, xT);
    hipLaunchKernelGGL(k_repack_w, dim3(2304 + 85), dim3(256), 0, stream,
                       w0_0, w0_1, w0_2, w0_3, w0_4, w1, w2, fc1_w,
                       Bp, w01T, w02T, w03T, w04T, fc1T, w1T, w2c);
    hipLaunchKernelGGL(k_conv, dim3(448), dim3(256), 0, stream, xT, Bp, b0_0, partial);
    hipLaunchKernelGGL(k_tail, dim3(16), dim3(1024), 0, stream, partial,
                       w01T, fc1T, w02T, w03T, w04T, w1T, w2c,
                       b0_1, b0_2, b0_3, b0_4, b1, b2, fc2_w, fc2_b, compat, sw,
                       (float*)d_out);
}